// Round 1
// baseline (356.142 us; speedup 1.0000x reference)
//
#include <hip/hip_runtime.h>
#include <math.h>

// ---------------------------------------------------------------------------
// Problem constants
// ---------------------------------------------------------------------------
#define NROWS 65536          // B*NAG = 8192*8
#define NB    8192           // B
// workspace layout (float offsets)
#define WS_A1   0            // 65536*64  pre-BN actor activations
#define WS_U    4194304      // 65536*64  h @ po1_w[:64]   (j-indexed half)
#define WS_V    8388608      // 65536*64  h @ po1_w[64:]   (i-indexed half)
#define WS_MU   12582912     // 65536*24
#define WS_SIG  14155776     // 65536*24
#define STAT_OFF  15728640   // 448 floats: asum asq usum usq vsum vsq cross
#define DERIV_OFF 15729088   // 256 + 384: ascale ashift pscale pshift | po2^T
// d_out layout (float offsets): x_out, h, KL
#define OUT_XOUT 0
#define OUT_H    917504
#define OUT_KL   5111808

__device__ __forceinline__ float sigmf(float x) { return 1.0f / (1.0f + __expf(-x)); }
__device__ __forceinline__ float tanhfast(float x) {
    x = fminf(fmaxf(x, -15.f), 15.f);
    float e = __expf(-2.f * x);
    return (1.f - e) / (1.f + e);
}

// ---------------------------------------------------------------------------
// K0: zero the global stat accumulators (ws is poisoned 0xAA before each call)
// ---------------------------------------------------------------------------
__global__ void k_init(float* __restrict__ ws) {
    int t = threadIdx.x;
    for (int i = t; i < 448; i += 256) ws[STAT_OFF + i] = 0.f;
}

// ---------------------------------------------------------------------------
// K1: fc1 -> GRU -> {a1, U, V} + BN stat partials.  64 rows/block, 256 thr.
// Each thread owns a 4x4 register tile; weights streamed from global (L1/L2),
// activations from LDS.
// ---------------------------------------------------------------------------
__global__ __launch_bounds__(256) void k_front(
    const float* __restrict__ inp, const float* __restrict__ hin,
    const float* __restrict__ fc1_w, const float* __restrict__ fc1_b,
    const float* __restrict__ w_ih, const float* __restrict__ w_hh,
    const float* __restrict__ b_ih, const float* __restrict__ b_hh,
    const float* __restrict__ aw1_w, const float* __restrict__ aw1_b,
    const float* __restrict__ po1_w,
    float* __restrict__ h_out, float* __restrict__ ws)
{
    __shared__ float s_in[64 * 100];   // inputs; reused as s_h (stride 68) later
    __shared__ float s_hin[64 * 68];
    __shared__ float s_x[64 * 68];
    __shared__ float s_stat[6 * 64];   // asum asq usum usq vsum vsq
    __shared__ float s_ub[8 * 64];
    __shared__ float s_vb[8 * 64];

    const int t = threadIdx.x;
    const int row0 = blockIdx.x * 64;

    for (int i = t; i < 6 * 64; i += 256) s_stat[i] = 0.f;
    for (int i = t; i < 8 * 64; i += 256) { s_ub[i] = 0.f; s_vb[i] = 0.f; }

    // stage inp (64x96) and h_in (64x64)
    {
        const float* gi = inp + (size_t)row0 * 96;
        for (int i = t; i < 64 * 24; i += 256) {
            int r = i / 24, kc = (i - r * 24) * 4;
            *(float4*)&s_in[r * 100 + kc] = *(const float4*)&gi[r * 96 + kc];
        }
        const float* gh = hin + (size_t)row0 * 64;
        for (int i = t; i < 64 * 16; i += 256) {
            int r = i >> 4, kc = (i & 15) * 4;
            *(float4*)&s_hin[r * 68 + kc] = *(const float4*)&gh[r * 64 + kc];
        }
    }
    __syncthreads();

    const int c0 = (t & 15) * 4;
    const int r0 = (t >> 4) * 4;

    // ---- P1: x = relu(inp @ fc1_w + fc1_b) ----
    {
        float acc[4][4];
        float bb[4]; *(float4*)bb = *(const float4*)&fc1_b[c0];
        #pragma unroll
        for (int i = 0; i < 4; i++)
            #pragma unroll
            for (int j = 0; j < 4; j++) acc[i][j] = bb[j];
        #pragma unroll 4
        for (int k = 0; k < 96; k++) {
            float w[4]; *(float4*)w = *(const float4*)&fc1_w[k * 64 + c0];
            #pragma unroll
            for (int i = 0; i < 4; i++) {
                float xv = s_in[(r0 + i) * 100 + k];
                #pragma unroll
                for (int j = 0; j < 4; j++) acc[i][j] += xv * w[j];
            }
        }
        #pragma unroll
        for (int i = 0; i < 4; i++) {
            float o[4];
            #pragma unroll
            for (int j = 0; j < 4; j++) o[j] = fmaxf(acc[i][j], 0.f);
            *(float4*)&s_x[(r0 + i) * 68 + c0] = *(float4*)o;
        }
    }
    __syncthreads();

    // ---- P2: GRU gates + nonlinearity ----
    {
        float ar[4][4], az[4][4], an[4][4], hn[4][4];
        float br[4], bz[4], bn_[4], bh[4], t0[4], t1[4];
        *(float4*)t0 = *(const float4*)&b_ih[c0];
        *(float4*)t1 = *(const float4*)&b_hh[c0];
        #pragma unroll
        for (int j = 0; j < 4; j++) br[j] = t0[j] + t1[j];
        *(float4*)t0 = *(const float4*)&b_ih[64 + c0];
        *(float4*)t1 = *(const float4*)&b_hh[64 + c0];
        #pragma unroll
        for (int j = 0; j < 4; j++) bz[j] = t0[j] + t1[j];
        *(float4*)bn_ = *(const float4*)&b_ih[128 + c0];
        *(float4*)bh  = *(const float4*)&b_hh[128 + c0];
        #pragma unroll
        for (int i = 0; i < 4; i++)
            #pragma unroll
            for (int j = 0; j < 4; j++) { ar[i][j] = br[j]; az[i][j] = bz[j]; an[i][j] = bn_[j]; hn[i][j] = bh[j]; }

        #pragma unroll 2
        for (int k = 0; k < 64; k++) {
            const float* wi = w_ih + k * 192 + c0;
            const float* wh = w_hh + k * 192 + c0;
            float wir[4], wiz[4], win[4], whr[4], whz[4], whn[4];
            *(float4*)wir = *(const float4*)&wi[0];
            *(float4*)wiz = *(const float4*)&wi[64];
            *(float4*)win = *(const float4*)&wi[128];
            *(float4*)whr = *(const float4*)&wh[0];
            *(float4*)whz = *(const float4*)&wh[64];
            *(float4*)whn = *(const float4*)&wh[128];
            #pragma unroll
            for (int i = 0; i < 4; i++) {
                float xv = s_x[(r0 + i) * 68 + k];
                float hv = s_hin[(r0 + i) * 68 + k];
                #pragma unroll
                for (int j = 0; j < 4; j++) {
                    ar[i][j] += xv * wir[j] + hv * whr[j];
                    az[i][j] += xv * wiz[j] + hv * whz[j];
                    an[i][j] += xv * win[j];
                    hn[i][j] += hv * whn[j];
                }
            }
        }
        float* s_h = s_in;   // reuse (stride 68); all s_in reads ended before barrier above
        #pragma unroll
        for (int i = 0; i < 4; i++) {
            float o[4];
            #pragma unroll
            for (int j = 0; j < 4; j++) {
                float r = sigmf(ar[i][j]);
                float z = sigmf(az[i][j]);
                float nt = tanhfast(an[i][j] + r * hn[i][j]);
                float hp = s_hin[(r0 + i) * 68 + c0 + j];
                o[j] = (1.f - z) * nt + z * hp;
            }
            *(float4*)&s_h[(r0 + i) * 68 + c0] = *(float4*)o;
            *(float4*)&h_out[(size_t)(row0 + r0 + i) * 64 + c0] = *(float4*)o;
        }
    }
    __syncthreads();

    // ---- P3: a1 = h@aw1_w + b,  U = h@po1_w[:64],  V = h@po1_w[64:]  + stats ----
    {
        const float* s_h = s_in;
        float a_[4][4], u_[4][4], v_[4][4];
        float ab[4]; *(float4*)ab = *(const float4*)&aw1_b[c0];
        #pragma unroll
        for (int i = 0; i < 4; i++)
            #pragma unroll
            for (int j = 0; j < 4; j++) { a_[i][j] = ab[j]; u_[i][j] = 0.f; v_[i][j] = 0.f; }
        #pragma unroll 2
        for (int k = 0; k < 64; k++) {
            float wa[4], wu[4], wv[4];
            *(float4*)wa = *(const float4*)&aw1_w[k * 64 + c0];
            *(float4*)wu = *(const float4*)&po1_w[k * 64 + c0];
            *(float4*)wv = *(const float4*)&po1_w[(64 + k) * 64 + c0];
            #pragma unroll
            for (int i = 0; i < 4; i++) {
                float hv = s_h[(r0 + i) * 68 + k];
                #pragma unroll
                for (int j = 0; j < 4; j++) {
                    a_[i][j] += hv * wa[j];
                    u_[i][j] += hv * wu[j];
                    v_[i][j] += hv * wv[j];
                }
            }
        }
        float* wsa = ws + WS_A1;
        float* wsu = ws + WS_U;
        float* wsv = ws + WS_V;
        #pragma unroll
        for (int i = 0; i < 4; i++) {
            *(float4*)&wsa[(size_t)(row0 + r0 + i) * 64 + c0] = *(float4*)a_[i];
            *(float4*)&wsu[(size_t)(row0 + r0 + i) * 64 + c0] = *(float4*)u_[i];
            *(float4*)&wsv[(size_t)(row0 + r0 + i) * 64 + c0] = *(float4*)v_[i];
        }
        const int g = r0 >> 3;   // b-group within block (rows 8g..8g+7)
        #pragma unroll
        for (int j = 0; j < 4; j++) {
            float sa = 0, sq = 0, su = 0, suq = 0, sv = 0, svq = 0;
            #pragma unroll
            for (int i = 0; i < 4; i++) {
                float x = a_[i][j]; sa += x; sq += x * x;
                float u = u_[i][j]; su += u; suq += u * u;
                float v = v_[i][j]; sv += v; svq += v * v;
            }
            atomicAdd(&s_stat[c0 + j], sa);
            atomicAdd(&s_stat[64 + c0 + j], sq);
            atomicAdd(&s_stat[128 + c0 + j], su);
            atomicAdd(&s_stat[192 + c0 + j], suq);
            atomicAdd(&s_stat[256 + c0 + j], sv);
            atomicAdd(&s_stat[320 + c0 + j], svq);
            atomicAdd(&s_ub[g * 64 + c0 + j], su);
            atomicAdd(&s_vb[g * 64 + c0 + j], sv);
        }
    }
    __syncthreads();
    if (t < 64) {
        float* gs = ws + STAT_OFF;
        atomicAdd(&gs[t],        s_stat[t]);
        atomicAdd(&gs[64 + t],   s_stat[64 + t]);
        atomicAdd(&gs[128 + t],  s_stat[128 + t]);
        atomicAdd(&gs[192 + t],  s_stat[192 + t]);
        atomicAdd(&gs[256 + t],  s_stat[256 + t]);
        atomicAdd(&gs[320 + t],  s_stat[320 + t]);
        float cr = 0.f;
        #pragma unroll
        for (int g = 0; g < 8; g++)
            cr += (s_ub[g * 64 + t] * 0.125f) * (s_vb[g * 64 + t] * 0.125f);
        atomicAdd(&gs[384 + t], cr);
    }
}

// ---------------------------------------------------------------------------
// K2: finalize BN scale/shift.  Var(U+V) = Var_u + Var_v + 2*(cross/B - Eu*Ev)
// Also transposes po2_w (64x6 -> 6x64) for uniform s_loads in K4.
// ---------------------------------------------------------------------------
__global__ void k_stats(const float* __restrict__ aw_g, const float* __restrict__ aw_be,
                        const float* __restrict__ po_g, const float* __restrict__ po_be,
                        const float* __restrict__ po1_b, const float* __restrict__ po2_w,
                        float* __restrict__ ws)
{
    const int t = threadIdx.x;
    const float* st = ws + STAT_OFF;
    float* dv = ws + DERIV_OFF;
    if (t < 64) {
        const float invN = 1.f / 65536.f;
        float am = st[t] * invN;
        float av = st[64 + t] * invN - am * am;
        float asc = aw_g[t] * rsqrtf(av + 1e-5f);
        dv[t] = asc;
        dv[64 + t] = aw_be[t] - asc * am;
        float Eu = st[128 + t] * invN;
        float vu = st[192 + t] * invN - Eu * Eu;
        float Ev = st[256 + t] * invN;
        float vv = st[320 + t] * invN - Ev * Ev;
        float cov = st[384 + t] * (1.f / 8192.f) - Eu * Ev;
        float my = Eu + Ev + po1_b[t];
        float vy = vu + vv + 2.f * cov;
        float psc = po_g[t] * rsqrtf(vy + 1e-5f);
        dv[128 + t] = psc;
        dv[192 + t] = po_be[t] + psc * (po1_b[t] - my);
    }
    for (int i = t; i < 384; i += 128) {
        int d = i >> 6, c = i & 63;
        dv[256 + i] = po2_w[c * 6 + d];     // po2^T [6][64]
    }
}

// ---------------------------------------------------------------------------
// K3: actor head: a=relu(bn(a1)); aw=a@aw2_w+b; mu/sigma/c; x_out=[h,c]@fc2_w+b
// 64 rows/block, 256 threads.
// ---------------------------------------------------------------------------
__global__ __launch_bounds__(256) void k_aw(
    float* __restrict__ ws, const float* __restrict__ h_glob,
    const float* __restrict__ noise,
    const float* __restrict__ aw2_w, const float* __restrict__ aw2_b,
    const float* __restrict__ fc2_w, const float* __restrict__ fc2_b,
    float* __restrict__ out)
{
    __shared__ float s_a[64 * 68];
    __shared__ float s_h[64 * 68];
    __shared__ float s_aw[64 * 52];
    __shared__ float s_c[64 * 28];
    const int t = threadIdx.x;
    const int row0 = blockIdx.x * 64;
    const float* a1 = ws + WS_A1;
    const float* dv = ws + DERIV_OFF;

    for (int i = t; i < 1024; i += 256) {
        int r = i >> 4, kc = (i & 15) * 4;
        float a_[4]; *(float4*)a_ = *(const float4*)&a1[(size_t)(row0 + r) * 64 + kc];
        float sc[4]; *(float4*)sc = *(const float4*)&dv[kc];
        float sf[4]; *(float4*)sf = *(const float4*)&dv[64 + kc];
        float o[4];
        #pragma unroll
        for (int j = 0; j < 4; j++) o[j] = fmaxf(sc[j] * a_[j] + sf[j], 0.f);
        *(float4*)&s_a[r * 68 + kc] = *(float4*)o;
        *(float4*)&s_h[r * 68 + kc] = *(const float4*)&h_glob[(size_t)(row0 + r) * 64 + kc];
    }
    __syncthreads();

    const int cg = t & 15, rg = t >> 4;
    const int c0 = cg * 4, r0 = rg * 4;
    if (cg < 12) {                      // 48 output cols
        float acc[4][4];
        float bb[4]; *(float4*)bb = *(const float4*)&aw2_b[c0];
        #pragma unroll
        for (int i = 0; i < 4; i++)
            #pragma unroll
            for (int j = 0; j < 4; j++) acc[i][j] = bb[j];
        #pragma unroll 2
        for (int k = 0; k < 64; k++) {
            float w[4]; *(float4*)w = *(const float4*)&aw2_w[k * 48 + c0];
            #pragma unroll
            for (int i = 0; i < 4; i++) {
                float av = s_a[(r0 + i) * 68 + k];
                #pragma unroll
                for (int j = 0; j < 4; j++) acc[i][j] += av * w[j];
            }
        }
        #pragma unroll
        for (int i = 0; i < 4; i++)
            *(float4*)&s_aw[(r0 + i) * 52 + c0] = *(float4*)acc[i];
    }
    __syncthreads();

    float* ws_mu = ws + WS_MU;
    float* ws_sig = ws + WS_SIG;
    for (int idx = t; idx < 1536; idx += 256) {
        int r = idx / 24, m = idx - r * 24;
        int grow = row0 + r;
        float mu = s_aw[r * 52 + m];
        float sg = fmaxf(__expf(s_aw[r * 52 + 24 + m]), 0.2f);
        ws_mu[(size_t)grow * 24 + m] = mu;
        ws_sig[(size_t)grow * 24 + m] = sg;
        s_c[r * 28 + m] = mu + sqrtf(sg) * noise[(size_t)grow * 24 + m];
    }
    __syncthreads();

    float* xout = out + OUT_XOUT;
    for (int o = t; o < 896; o += 256) {
        int r = o / 14, c = o - r * 14;
        float acc = fc2_b[c];
        #pragma unroll 4
        for (int k = 0; k < 64; k++) acc += s_h[r * 68 + k] * fc2_w[k * 14 + c];
        #pragma unroll 4
        for (int k = 0; k < 24; k++) acc += s_c[r * 28 + k] * fc2_w[(64 + k) * 14 + c];
        xout[(size_t)(row0 + r) * 14 + c] = acc;
    }
}

// ---------------------------------------------------------------------------
// K4: critic head: y[b,i,j]=U[b,j]+V[b,i]; p=relu(bn(y)); out6=p@po2; KL.
// 8 b per block, 128 threads; thread owns (i, j0..j0+3) for one b.
// ---------------------------------------------------------------------------
__global__ __launch_bounds__(128) void k_po(
    const float* __restrict__ ws, const float* __restrict__ po2_b,
    float* __restrict__ kl_out)
{
    __shared__ float s_U[64 * 68];
    __shared__ float s_V[64 * 68];
    __shared__ float s_out[64 * 48];
    __shared__ float s_kl[64];
    const int t = threadIdx.x;
    const int b0 = blockIdx.x * 8;
    const float* U = ws + WS_U;
    const float* V = ws + WS_V;
    const float* dv = ws + DERIV_OFF;
    const float* psc = dv + 128;
    const float* psh = dv + 192;
    const float* p2t = dv + 256;   // [6][64]

    for (int i = t; i < 1024; i += 128) {
        int r = i >> 4, kc = (i & 15) * 4;
        *(float4*)&s_U[r * 68 + kc] = *(const float4*)&U[(size_t)(b0 * 8 + r) * 64 + kc];
        *(float4*)&s_V[r * 68 + kc] = *(const float4*)&V[(size_t)(b0 * 8 + r) * 64 + kc];
    }
    __syncthreads();

    const int bl = t >> 4;            // local b (0..7)
    const int rem = t & 15;
    const int i_ = rem >> 1;          // i (0..7)
    const int j0 = (rem & 1) * 4;     // j base (0 or 4)
    float acc[4][6];
    #pragma unroll
    for (int jj = 0; jj < 4; jj++)
        #pragma unroll
        for (int d = 0; d < 6; d++) acc[jj][d] = 0.f;

    for (int c = 0; c < 64; c += 4) {
        float vv[4]; *(float4*)vv = *(const float4*)&s_V[(bl * 8 + i_) * 68 + c];
        float ps[4]; *(float4*)ps = *(const float4*)&psc[c];   // uniform -> s_load
        float pf[4]; *(float4*)pf = *(const float4*)&psh[c];
        float w[6][4];
        #pragma unroll
        for (int d = 0; d < 6; d++) *(float4*)w[d] = *(const float4*)&p2t[d * 64 + c];
        #pragma unroll
        for (int jj = 0; jj < 4; jj++) {
            float uu[4]; *(float4*)uu = *(const float4*)&s_U[(bl * 8 + j0 + jj) * 68 + c];
            float p[4];
            #pragma unroll
            for (int q = 0; q < 4; q++) p[q] = fmaxf(ps[q] * (uu[q] + vv[q]) + pf[q], 0.f);
            #pragma unroll
            for (int d = 0; d < 6; d++)
                acc[jj][d] += p[0] * w[d][0] + p[1] * w[d][1] + p[2] * w[d][2] + p[3] * w[d][3];
        }
    }
    #pragma unroll
    for (int jj = 0; jj < 4; jj++)
        #pragma unroll
        for (int d = 0; d < 6; d++)
            s_out[(bl * 8 + i_) * 48 + (j0 + jj) * 6 + d] = acc[jj][d] + po2_b[d];
    __syncthreads();

    if (t < 64) {
        const float* ws_mu = ws + WS_MU;
        const float* ws_sig = ws + WS_SIG;
        int grow = (b0 + (t >> 3)) * 8 + (t & 7);
        float s = 0.f;
        #pragma unroll
        for (int m4 = 0; m4 < 6; m4++) {
            float mu0[4]; *(float4*)mu0 = *(const float4*)&ws_mu[(size_t)grow * 24 + m4 * 4];
            float sg0[4]; *(float4*)sg0 = *(const float4*)&ws_sig[(size_t)grow * 24 + m4 * 4];
            #pragma unroll
            for (int q = 0; q < 4; q++) {
                int m = m4 * 4 + q;
                float mu1 = s_out[t * 48 + m];
                float sg1 = fmaxf(__expf(s_out[t * 48 + 24 + m]), 0.2f);
                float d0 = mu0[q] - mu1;
                s += __logf(sg1 / sg0[q]) + (sg0[q] + d0 * d0) / sg1 - 1.f;
            }
        }
        s_kl[t] = s;
    }
    __syncthreads();
    if (t < 8) {
        float s = 0.f;
        #pragma unroll
        for (int i = 0; i < 8; i++) s += s_kl[t * 8 + i];
        kl_out[b0 + t] = s * (0.5f / 192.f);
    }
}

// ---------------------------------------------------------------------------
extern "C" void kernel_launch(void* const* d_in, const int* in_sizes, int n_in,
                              void* d_out, int out_size, void* d_ws, size_t ws_size,
                              hipStream_t stream)
{
    (void)in_sizes; (void)n_in; (void)out_size; (void)ws_size;
    const float* inp   = (const float*)d_in[0];
    const float* hin   = (const float*)d_in[1];
    const float* noise = (const float*)d_in[2];
    const float* fc1_w = (const float*)d_in[3];
    const float* fc1_b = (const float*)d_in[4];
    const float* w_ih  = (const float*)d_in[5];
    const float* w_hh  = (const float*)d_in[6];
    const float* b_ih  = (const float*)d_in[7];
    const float* b_hh  = (const float*)d_in[8];
    const float* aw1_w = (const float*)d_in[9];
    const float* aw1_b = (const float*)d_in[10];
    const float* aw_g  = (const float*)d_in[11];
    const float* aw_be = (const float*)d_in[12];
    const float* aw2_w = (const float*)d_in[13];
    const float* aw2_b = (const float*)d_in[14];
    const float* po1_w = (const float*)d_in[15];
    const float* po1_b = (const float*)d_in[16];
    const float* po_g  = (const float*)d_in[17];
    const float* po_be = (const float*)d_in[18];
    const float* po2_w = (const float*)d_in[19];
    const float* po2_b = (const float*)d_in[20];
    const float* fc2_w = (const float*)d_in[21];
    const float* fc2_b = (const float*)d_in[22];
    float* out = (float*)d_out;
    float* ws  = (float*)d_ws;

    hipLaunchKernelGGL(k_init,  dim3(1),    dim3(256), 0, stream, ws);
    hipLaunchKernelGGL(k_front, dim3(1024), dim3(256), 0, stream,
                       inp, hin, fc1_w, fc1_b, w_ih, w_hh, b_ih, b_hh,
                       aw1_w, aw1_b, po1_w, out + OUT_H, ws);
    hipLaunchKernelGGL(k_stats, dim3(1),    dim3(128), 0, stream,
                       aw_g, aw_be, po_g, po_be, po1_b, po2_w, ws);
    hipLaunchKernelGGL(k_aw,    dim3(1024), dim3(256), 0, stream,
                       ws, out + OUT_H, noise, aw2_w, aw2_b, fc2_w, fc2_b, out);
    hipLaunchKernelGGL(k_po,    dim3(1024), dim3(128), 0, stream,
                       ws, po2_b, out + OUT_KL);
}